// Round 7
// baseline (201.102 us; speedup 1.0000x reference)
//
#include <hip/hip_runtime.h>
#include <hip/hip_bf16.h>
#include <stdint.h>

// GraphAttentionLayer: B=8, S=2048, F=128, H=4, D=32
// proj: Wh[b,h,s,d] (row-major) AND WhT[b,h,d,s] (transposed) via bf16 MFMA
// attn: out[b,s,h*32+d] = softmax_t(mask(Wh_q . Wh_t / sqrt(D))) @ Wh
//   fixed-max softmax (max=0), swapped QK^T and swapped PV, t-split across
//   blocks (nchunks) + q-split across waves (8 waves = 4 heads x 2 q-subtiles).

namespace {
constexpr int S = 2048;
constexpr int F = 128;
constexpr int H = 4;
constexpr int D = 32;

typedef __attribute__((ext_vector_type(4))) float f32x4;
typedef __attribute__((ext_vector_type(8))) short s16x8;
typedef __attribute__((ext_vector_type(4))) short s16x4;

__device__ __forceinline__ short f2bf(float f) {
  __hip_bfloat16 h = __float2bfloat16(f);
  short s; __builtin_memcpy(&s, &h, sizeof(s)); return s;
}
__device__ __forceinline__ float bf2f(short s) {
  __hip_bfloat16 h; __builtin_memcpy(&h, &s, sizeof(s));
  return __bfloat162float(h);
}
// pack 2 floats -> 2 bf16 in one u32 (v_cvt_pk_bf16_f32)
__device__ __forceinline__ unsigned pkbf(float a, float b) {
  __hip_bfloat162 h = __float22bfloat162_rn(float2{a, b});
  unsigned u; __builtin_memcpy(&u, &h, 4); return u;
}

__global__ __launch_bounds__(256) void gat_proj(const float* __restrict__ feat,
                                                const float* __restrict__ W,
                                                short* __restrict__ Wh,
                                                short* __restrict__ WhT) {
  __shared__ __align__(16) short ftile[64][136];  // 64 rows x 128 f (pad 8)
  const int tid = threadIdx.x;
  const int w = tid >> 6;            // wave = head
  const int l = tid & 63;
  const int ln = l & 15, lg = l >> 4, g4 = (l >> 4) * 4;
  const int row0 = blockIdx.x * 64;  // flat row in [B*S]
  const int b = row0 >> 11;
  const int sl0 = row0 & (S - 1);

#pragma unroll
  for (int i = 0; i < 4; ++i) {
    int c = i * 256 + tid;           // 8-float chunk
    int r = c >> 4, c8 = (c & 15) * 8;
    const float* src = feat + (size_t)(row0 + r) * F + c8;
    float4 v0 = *(const float4*)src;
    float4 v1 = *(const float4*)(src + 4);
    s16x8 v;
    v[0]=f2bf(v0.x); v[1]=f2bf(v0.y); v[2]=f2bf(v0.z); v[3]=f2bf(v0.w);
    v[4]=f2bf(v1.x); v[5]=f2bf(v1.y); v[6]=f2bf(v1.z); v[7]=f2bf(v1.w);
    *(s16x8*)&ftile[r][c8] = v;
  }

  // W fragments: B[k][n], n = nt*16+ln, k = ks*32+lg*8+j
  s16x8 bfr[4][2];
#pragma unroll
  for (int ks = 0; ks < 4; ++ks)
#pragma unroll
    for (int nt = 0; nt < 2; ++nt) {
      s16x8 v;
#pragma unroll
      for (int j = 0; j < 8; ++j)
        v[j] = f2bf(W[((size_t)w * F + ks*32 + lg*8 + j) * D + nt*16 + ln]);
      bfr[ks][nt] = v;
    }
  __syncthreads();

  const f32x4 z4 = {0.f, 0.f, 0.f, 0.f};
#pragma unroll
  for (int mt = 0; mt < 4; ++mt) {
    s16x8 a[4];
#pragma unroll
    for (int ks = 0; ks < 4; ++ks)
      a[ks] = *(const s16x8*)&ftile[mt*16 + ln][ks*32 + lg*8];
#pragma unroll
    for (int nt = 0; nt < 2; ++nt) {
      f32x4 c = z4;
#pragma unroll
      for (int ks = 0; ks < 4; ++ks)
        c = __builtin_amdgcn_mfma_f32_16x16x32_bf16(a[ks], bfr[ks][nt], c, 0, 0, 0);
      s16x4 tv;
#pragma unroll
      for (int r = 0; r < 4; ++r) {
        tv[r] = f2bf(c[r]);
        int srow = row0 + mt*16 + g4 + r;
        int s = srow & (S - 1);
        Wh[(((size_t)b * H + w) * S + s) * D + nt*16 + ln] = tv[r];
      }
      *(s16x4*)&WhT[(((size_t)b * H + w) * D + nt*16 + ln) * S + sl0 + mt*16 + g4] = tv;
    }
  }
}

__global__ __launch_bounds__(512, 8) void gat_attn(const int* __restrict__ adj,
                                                   const short* __restrict__ Wh,
                                                   const short* __restrict__ WhT,
                                                   float* __restrict__ out,
                                                   float* __restrict__ PO,
                                                   float* __restrict__ PS,
                                                   int tiles) {
  // LDS: u16 0/FFFF mask (pad-72 rows, dbuf) + per-wave P tiles = 9216+16384 B
  __shared__ __align__(16) unsigned short maskm[2][32][72];
  __shared__ __align__(16) short ptl[8][16][64];   // P [q][t], granule-swizzled

  const int tid = threadIdx.x;
  const int ww = tid >> 6;           // wave 0..7
  const int h = ww >> 1;             // head
  const int qtw = ww & 1;            // q-subtile (16 rows)
  const int l = tid & 63;
  const int ln = l & 15, lg = l >> 4, g4 = (l >> 4) * 4;
  const int e3 = ln & 7;
  const int lh = lg & 1;

  // XCD-chunked bijective swizzle (grid % 8 == 0)
  const int N = gridDim.x;
  const int rbid = ((int)blockIdx.x & 7) * (N >> 3) + ((int)blockIdx.x >> 3);
  const int c = rbid >> 9;           // t-chunk
  const int g = rbid & 511;
  const int b = g >> 6;
  const int s0 = (g & 63) * 32;
  const int it0 = c * tiles;

  const short* WhBH = Wh + ((size_t)b * H + h) * S * D;
  const short* WhTBH = WhT + ((size_t)b * H + h) * D * S;
  short* pw = &ptl[ww][0][0];

  // adj staging: thread -> (row = tid>>4, 4 t at (tid&15)*4), one int4 each
  const int arow = tid >> 4;                    // 0..31
  const int c4 = (tid & 15) * 4;
  const int* adjTh = adj + (size_t)b * S * S + (size_t)(s0 + arow) * S
                     + (size_t)it0 * 64 + c4;

  // Q fragment (B-operand of swapped QK^T), prescaled by log2(e)/sqrt(D)
  const float cs = 0.25503486f;
  s16x8 qf;
  {
    s16x8 v = *(const s16x8*)&WhBH[(size_t)(s0 + qtw*16 + ln) * D + lg*8];
#pragma unroll
    for (int j = 0; j < 8; ++j) qf[j] = f2bf(bf2f(v[j]) * cs);
  }

  const f32x4 z4 = {0.f, 0.f, 0.f, 0.f};
  f32x4 accO[2];                     // [dt] of O^T (cols = this wave's 16 q)
  accO[0] = z4; accO[1] = z4;
  float psum = 0.f;                  // partial rowsum (q = qtw*16+ln, t-slice)

  // ---- prologue: tile it0 ----
  {
    int4 a = *(const int4*)adjTh;
    uint2 mw;
    mw.x = (a.x ? 0xFFFFu : 0u) | (a.y ? 0xFFFF0000u : 0u);
    mw.y = (a.z ? 0xFFFFu : 0u) | (a.w ? 0xFFFF0000u : 0u);
    *(uint2*)&maskm[0][arow][c4] = mw;
  }
  s16x8 kf[4];
  s16x8 av[2][2];                    // V^T A-frags: [dt][kt]
  {
    const size_t t0 = (size_t)it0 * 64;
#pragma unroll
    for (int mt = 0; mt < 4; ++mt)
      kf[mt] = *(const s16x8*)&WhBH[(t0 + mt*16 + ln) * D + lg*8];
#pragma unroll
    for (int dt = 0; dt < 2; ++dt)
#pragma unroll
      for (int kt = 0; kt < 2; ++kt)
        av[dt][kt] = *(const s16x8*)&WhTBH[(size_t)(dt*16 + ln) * S + t0 + kt*32 + lg*8];
  }
  __syncthreads();

#pragma unroll 1
  for (int i = 0; i < tiles; ++i) {
    const int cur = i & 1;
    const bool pf = (i + 1 < tiles);
    const int iLd = pf ? i + 1 : i;           // clamped next-tile index
    const size_t tnl = (size_t)(it0 + iLd) * 64;

    // top: issue next-tile adj load (full-body latency cover)
    int4 an = *(const int4*)(adjTh + (size_t)iLd * 64);

    // QK^T + softmax, mt-blocked; kf[mt] reloaded in place right after use
#pragma unroll
    for (int mt = 0; mt < 4; ++mt) {
      f32x4 sv = __builtin_amdgcn_mfma_f32_16x16x32_bf16(kf[mt], qf, z4, 0, 0, 0);
      kf[mt] = *(const s16x8*)&WhBH[(tnl + mt*16 + ln) * D + lg*8];

      uint2 mm = *(const uint2*)&maskm[cur][qtw*16 + ln][mt*16 + g4];
      float p0 = __builtin_amdgcn_exp2f(sv[0]);
      float p1 = __builtin_amdgcn_exp2f(sv[1]);
      float p2 = __builtin_amdgcn_exp2f(sv[2]);
      float p3 = __builtin_amdgcn_exp2f(sv[3]);
      uint2 pk;
      pk.x = pkbf(p0, p1) & mm.x;
      pk.y = pkbf(p2, p3) & mm.y;
      // accumulate masked probabilities into the partial rowsum
      float m0 = bf2f((short)(pk.x & 0xFFFFu));
      float m1 = bf2f((short)(pk.x >> 16));
      float m2 = bf2f((short)(pk.y & 0xFFFFu));
      float m3 = bf2f((short)(pk.y >> 16));
      psum += (m0 + m1) + (m2 + m3);
      const int pgo = ((mt*2 + (lg >> 1)) ^ e3) * 8 + lh * 4;
      *(uint2*)&pw[ln*64 + pgo] = pk;
    }

    // P fragments (same-wave LDS, in-order after writes)
    s16x8 ap[2];
#pragma unroll
    for (int kt = 0; kt < 2; ++kt)
      ap[kt] = *(const s16x8*)&pw[ln*64 + (((kt*4 + lg) ^ e3) << 3)];

    // swapped PV: O^T[d][q] += V^T[d][t] * P[q][t]
#pragma unroll
    for (int dt = 0; dt < 2; ++dt)
#pragma unroll
      for (int kt = 0; kt < 2; ++kt)
        accO[dt] = __builtin_amdgcn_mfma_f32_16x16x32_bf16(
            av[dt][kt], ap[kt], accO[dt], 0, 0, 0);

    // av reload (next use: next-iter PV; WhT is L2-hot)
#pragma unroll
    for (int dt = 0; dt < 2; ++dt)
#pragma unroll
      for (int kt = 0; kt < 2; ++kt)
        av[dt][kt] = *(const s16x8*)&WhTBH[(size_t)(dt*16 + ln) * S + tnl + kt*32 + lg*8];

    // commit next mask tile
    if (pf) {
      uint2 mw;
      mw.x = (an.x ? 0xFFFFu : 0u) | (an.y ? 0xFFFF0000u : 0u);
      mw.y = (an.z ? 0xFFFFu : 0u) | (an.w ? 0xFFFF0000u : 0u);
      *(uint2*)&maskm[cur ^ 1][arow][c4] = mw;
    }
    __syncthreads();
  }

  // ---- epilogue: reduce psum across the 4 lg-groups (t-slices) ----
  psum += __shfl_xor(psum, 16, 64);
  psum += __shfl_xor(psum, 32, 64);

  if (PO == nullptr) {
    float inv = 1.0f / psum;
#pragma unroll
    for (int dt = 0; dt < 2; ++dt) {
      f32x4 o;
#pragma unroll
      for (int r = 0; r < 4; ++r) o[r] = accO[dt][r] * inv;
      *(f32x4*)&out[((size_t)b * S + s0 + qtw*16 + ln) * (H * D) + h*32 + dt*16 + g4] = o;
    }
  } else {
    const size_t pbase = (size_t)rbid * H + h;
    float* po = PO + pbase * 1024;
#pragma unroll
    for (int dt = 0; dt < 2; ++dt)
      *(f32x4*)&po[(qtw*16 + ln)*32 + dt*16 + g4] = accO[dt];
    if (lg == 0) PS[pbase * 32 + qtw*16 + ln] = psum;
  }
}

__global__ __launch_bounds__(256) void gat_reduce(const float* __restrict__ PO,
                                                  const float* __restrict__ PS,
                                                  float* __restrict__ out,
                                                  int nchunks) {
  const int f4 = blockIdx.x * 256 + threadIdx.x;  // f32x4 index over out
  const int d4 = f4 & 31;            // 32 f32x4 per s-row (128 floats)
  const int h = d4 >> 3;
  const int dq = d4 & 7;
  const int s_flat = f4 >> 5;        // b*2048 + s
  const int b = s_flat >> 11, s = s_flat & 2047;
  const int g = b * 64 + (s >> 5), q = s & 31;

  f32x4 acc = {0.f, 0.f, 0.f, 0.f};
  float ps = 0.f;
  for (int c = 0; c < nchunks; ++c) {
    size_t pbase = ((size_t)(c * 512 + g)) * H + h;
    acc += *(const f32x4*)&PO[pbase * 1024 + q*32 + dq*4];
    ps += PS[pbase * 32 + q];
  }
  float inv = 1.0f / ps;
  f32x4 o = acc * inv;
  *(f32x4*)&out[(size_t)f4 * 4] = o;
}

}  // namespace

extern "C" void kernel_launch(void* const* d_in, const int* in_sizes, int n_in,
                              void* d_out, int out_size, void* d_ws, size_t ws_size,
                              hipStream_t stream) {
  const float* feat = (const float*)d_in[0];   // [8,2048,128] f32
  const int* adj    = (const int*)d_in[1];     // [8,2048,2048] i32
  const float* W    = (const float*)d_in[2];   // [4,128,32] f32
  float* out        = (float*)d_out;           // [8,2048,128] f32

  short* Wh  = (short*)d_ws;                             // 4 MiB bf16
  short* WhT = Wh + (size_t)8 * H * S * D;               // 4 MiB bf16
  const size_t whbytes = (size_t)2 * 8 * H * S * D * sizeof(short);
  const size_t chunkPO = (size_t)512 * H * 1024 * sizeof(float);  // 8 MiB
  const size_t chunkPS = (size_t)512 * H * 32 * sizeof(float);    // 256 KiB

  int nchunks = 1;
  if (ws_size >= whbytes + 2 * (chunkPO + chunkPS)) nchunks = 2;

  float* PO = nullptr;
  float* PS = nullptr;
  if (nchunks > 1) {
    PO = (float*)((char*)d_ws + whbytes);
    PS = (float*)((char*)d_ws + whbytes + (size_t)nchunks * chunkPO);
  }

  gat_proj<<<(8 * S) / 64, 256, 0, stream>>>(feat, W, Wh, WhT);
  gat_attn<<<512 * nchunks, 512, 0, stream>>>(adj, Wh, WhT, out, PO, PS, 32 / nchunks);
  if (nchunks > 1) gat_reduce<<<2048, 256, 0, stream>>>(PO, PS, out, nchunks);
}

// Round 8
// 73.318 us; speedup vs baseline: 2.7429x; 2.7429x over previous
//
#include <hip/hip_runtime.h>
#include <hip/hip_bf16.h>
#include <stdint.h>

// GraphAttentionLayer: B=8, S=2048, F=128, H=4, D=32
// proj: Wh[b,h,s,d] (row-major) AND WhT[b,h,d,s] (transposed) via bf16 MFMA
// attn: out[b,s,h*32+d] = softmax_t(mask(Wh_q . Wh_t / sqrt(D))) @ Wh
//   fixed-max softmax (max=0), swapped QK^T and swapped PV, t-split across
//   blocks. K rows loaded PERMUTED so softmax output registers ARE the PV
//   B-fragments (no P round-trip through LDS, no shuffles).

namespace {
constexpr int S = 2048;
constexpr int F = 128;
constexpr int H = 4;
constexpr int D = 32;

typedef __attribute__((ext_vector_type(4))) float f32x4;
typedef __attribute__((ext_vector_type(8))) short s16x8;
typedef __attribute__((ext_vector_type(4))) short s16x4;

__device__ __forceinline__ short f2bf(float f) {
  __hip_bfloat16 h = __float2bfloat16(f);
  short s; __builtin_memcpy(&s, &h, sizeof(s)); return s;
}
__device__ __forceinline__ float bf2f(short s) {
  __hip_bfloat16 h; __builtin_memcpy(&h, &s, sizeof(s));
  return __bfloat162float(h);
}
// pack 2 floats -> 2 bf16 in one u32 (v_cvt_pk_bf16_f32)
__device__ __forceinline__ unsigned pkbf(float a, float b) {
  __hip_bfloat162 h = __float22bfloat162_rn(float2{a, b});
  unsigned u; __builtin_memcpy(&u, &h, 4); return u;
}
__device__ __forceinline__ s16x8 mkfrag(uint2 a, uint2 b) {
  union { unsigned u[4]; s16x8 s; } x;
  x.u[0] = a.x; x.u[1] = a.y; x.u[2] = b.x; x.u[3] = b.y;
  return x.s;
}

__global__ __launch_bounds__(256) void gat_proj(const float* __restrict__ feat,
                                                const float* __restrict__ W,
                                                short* __restrict__ Wh,
                                                short* __restrict__ WhT) {
  __shared__ __align__(16) short ftile[64][136];  // 64 rows x 128 f (pad 8)
  const int tid = threadIdx.x;
  const int w = tid >> 6;            // wave = head
  const int l = tid & 63;
  const int ln = l & 15, lg = l >> 4, g4 = (l >> 4) * 4;
  const int row0 = blockIdx.x * 64;  // flat row in [B*S]
  const int b = row0 >> 11;
  const int sl0 = row0 & (S - 1);

#pragma unroll
  for (int i = 0; i < 4; ++i) {
    int c = i * 256 + tid;           // 8-float chunk
    int r = c >> 4, c8 = (c & 15) * 8;
    const float* src = feat + (size_t)(row0 + r) * F + c8;
    float4 v0 = *(const float4*)src;
    float4 v1 = *(const float4*)(src + 4);
    s16x8 v;
    v[0]=f2bf(v0.x); v[1]=f2bf(v0.y); v[2]=f2bf(v0.z); v[3]=f2bf(v0.w);
    v[4]=f2bf(v1.x); v[5]=f2bf(v1.y); v[6]=f2bf(v1.z); v[7]=f2bf(v1.w);
    *(s16x8*)&ftile[r][c8] = v;
  }

  // W fragments: B[k][n], n = nt*16+ln, k = ks*32+lg*8+j
  s16x8 bfr[4][2];
#pragma unroll
  for (int ks = 0; ks < 4; ++ks)
#pragma unroll
    for (int nt = 0; nt < 2; ++nt) {
      s16x8 v;
#pragma unroll
      for (int j = 0; j < 8; ++j)
        v[j] = f2bf(W[((size_t)w * F + ks*32 + lg*8 + j) * D + nt*16 + ln]);
      bfr[ks][nt] = v;
    }
  __syncthreads();

  const f32x4 z4 = {0.f, 0.f, 0.f, 0.f};
#pragma unroll
  for (int mt = 0; mt < 4; ++mt) {
    s16x8 a[4];
#pragma unroll
    for (int ks = 0; ks < 4; ++ks)
      a[ks] = *(const s16x8*)&ftile[mt*16 + ln][ks*32 + lg*8];
#pragma unroll
    for (int nt = 0; nt < 2; ++nt) {
      f32x4 c = z4;
#pragma unroll
      for (int ks = 0; ks < 4; ++ks)
        c = __builtin_amdgcn_mfma_f32_16x16x32_bf16(a[ks], bfr[ks][nt], c, 0, 0, 0);
      s16x4 tv;
#pragma unroll
      for (int r = 0; r < 4; ++r) {
        tv[r] = f2bf(c[r]);
        int srow = row0 + mt*16 + g4 + r;
        int s = srow & (S - 1);
        Wh[(((size_t)b * H + w) * S + s) * D + nt*16 + ln] = tv[r];
      }
      *(s16x4*)&WhT[(((size_t)b * H + w) * D + nt*16 + ln) * S + sl0 + mt*16 + g4] = tv;
    }
  }
}

__global__ __launch_bounds__(256, 4) void gat_attn(const int* __restrict__ adj,
                                                   const short* __restrict__ Wh,
                                                   const short* __restrict__ WhT,
                                                   float* __restrict__ out,
                                                   float* __restrict__ PO,
                                                   float* __restrict__ PS,
                                                   int tiles) {
  // LDS: only the u16 0/FFFF mask tile (stride-76 rows, dbuf) = 9728 B
  __shared__ __align__(16) unsigned short maskm[2][32][76];

  const int tid = threadIdx.x;
  const int w = tid >> 6;            // wave = head
  const int l = tid & 63;
  const int ln = l & 15, lg = l >> 4, g4 = (l >> 4) * 4;

  // XCD-chunked bijective swizzle (grid % 8 == 0)
  const int N = gridDim.x;
  const int rbid = ((int)blockIdx.x & 7) * (N >> 3) + ((int)blockIdx.x >> 3);
  const int c = rbid >> 9;           // t-chunk
  const int g = rbid & 511;
  const int b = g >> 6;
  const int s0 = (g & 63) * 32;
  const int it0 = c * tiles;

  const short* WhBH = Wh + ((size_t)b * H + w) * S * D;
  const short* WhTBH = WhT + ((size_t)b * H + w) * D * S;

  // adj staging: thread (arow = tid>>3, gc = tid&7) covers 8 t-values
  const int arow = tid >> 3;                    // 0..31
  const int gc = tid & 7;
  const int* adjTh = adj + (size_t)b * S * S + (size_t)(s0 + arow) * S
                     + (size_t)it0 * 64 + gc * 8;

  // Permuted K-row offsets: A row m=ln of QK^T mt-block holds K[t0 + toff(mt)]
  // toff(mt, ln) = 32*(mt>>1) + 8*(ln>>2) + 4*(mt&1) + (ln&3)
  int toff[4];
#pragma unroll
  for (int mt = 0; mt < 4; ++mt)
    toff[mt] = 32*(mt >> 1) + 8*(ln >> 2) + 4*(mt & 1) + (ln & 3);

  // Q fragments (B-operand of swapped QK^T), prescaled by log2(e)/sqrt(D)
  const float cs = 0.25503486f;
  s16x8 qf[2];
#pragma unroll
  for (int qt = 0; qt < 2; ++qt) {
    s16x8 v = *(const s16x8*)&WhBH[(size_t)(s0 + qt*16 + ln) * D + lg*8];
    s16x8 o;
#pragma unroll
    for (int j = 0; j < 8; ++j) o[j] = f2bf(bf2f(v[j]) * cs);
    qf[qt] = o;
  }

  s16x8 onesf;                       // bf16 1.0 broadcast (A-frag for rowsum)
#pragma unroll
  for (int j = 0; j < 8; ++j) onesf[j] = (short)0x3F80;

  const f32x4 z4 = {0.f, 0.f, 0.f, 0.f};
  f32x4 accO[2][2];                  // [dt][qt] of O^T
  f32x4 accP[2];                     // rowsum per qt (all 4 regs identical)
#pragma unroll
  for (int i = 0; i < 2; ++i) {
    accP[i] = z4;
#pragma unroll
    for (int j = 0; j < 2; ++j) accO[i][j] = z4;
  }

  // ---- prologue: tile it0 ----
  {
    int4 a0 = *(const int4*)adjTh;
    int4 a1 = *(const int4*)(adjTh + 4);
    uint2 u0, u1;
    u0.x = (a0.x ? 0xFFFFu : 0u) | (a0.y ? 0xFFFF0000u : 0u);
    u0.y = (a0.z ? 0xFFFFu : 0u) | (a0.w ? 0xFFFF0000u : 0u);
    u1.x = (a1.x ? 0xFFFFu : 0u) | (a1.y ? 0xFFFF0000u : 0u);
    u1.y = (a1.z ? 0xFFFFu : 0u) | (a1.w ? 0xFFFF0000u : 0u);
    *(uint2*)&maskm[0][arow][gc * 8] = u0;
    *(uint2*)&maskm[0][arow][gc * 8 + 4] = u1;
  }
  s16x8 kf[4];                       // permuted K rows
  s16x8 av[2][2];                    // V^T A-frags: [dt][kt]
  {
    const size_t t0 = (size_t)it0 * 64;
#pragma unroll
    for (int mt = 0; mt < 4; ++mt)
      kf[mt] = *(const s16x8*)&WhBH[(t0 + toff[mt]) * D + lg*8];
#pragma unroll
    for (int dt = 0; dt < 2; ++dt)
#pragma unroll
      for (int kt = 0; kt < 2; ++kt)
        av[dt][kt] = *(const s16x8*)&WhTBH[(size_t)(dt*16 + ln) * S + t0 + kt*32 + lg*8];
  }
  __syncthreads();

#pragma unroll 1
  for (int i = 0; i < tiles; ++i) {
    const int cur = i & 1;
    const bool pf = (i + 1 < tiles);
    const int iLd = pf ? i + 1 : i;           // clamped next-tile index
    const size_t tnl = (size_t)(it0 + iLd) * 64;

    // top: issue next-tile adj loads (full-body latency cover)
    int4 a0n = *(const int4*)(adjTh + (size_t)iLd * 64);
    int4 a1n = *(const int4*)(adjTh + (size_t)iLd * 64 + 4);

    // QK^T (permuted rows) + softmax, mt-blocked; kf reloaded right after use
    uint2 pks[2][4];                 // packed masked P, [qt][mt]
#pragma unroll
    for (int mt = 0; mt < 4; ++mt) {
      f32x4 sA = __builtin_amdgcn_mfma_f32_16x16x32_bf16(kf[mt], qf[0], z4, 0, 0, 0);
      f32x4 sB = __builtin_amdgcn_mfma_f32_16x16x32_bf16(kf[mt], qf[1], z4, 0, 0, 0);
      kf[mt] = *(const s16x8*)&WhBH[(tnl + toff[mt]) * D + lg*8];

      // D rows at this lane: t = 32*(mt>>1) + 8*lg + 4*(mt&1) + r
      const int tb = 32*(mt >> 1) + 8*lg + 4*(mt & 1);
      uint2 mmA = *(const uint2*)&maskm[cur][ln][tb];
      uint2 mmB = *(const uint2*)&maskm[cur][16 + ln][tb];
      uint2 pa, pb;
      pa.x = pkbf(__builtin_amdgcn_exp2f(sA[0]), __builtin_amdgcn_exp2f(sA[1])) & mmA.x;
      pa.y = pkbf(__builtin_amdgcn_exp2f(sA[2]), __builtin_amdgcn_exp2f(sA[3])) & mmA.y;
      pb.x = pkbf(__builtin_amdgcn_exp2f(sB[0]), __builtin_amdgcn_exp2f(sB[1])) & mmB.x;
      pb.y = pkbf(__builtin_amdgcn_exp2f(sB[2]), __builtin_amdgcn_exp2f(sB[3])) & mmB.y;
      pks[0][mt] = pa;
      pks[1][mt] = pb;
    }

    // PV B-fragments are register concatenations (no LDS, no shuffle)
    s16x8 ap[2][2];
#pragma unroll
    for (int qt = 0; qt < 2; ++qt)
#pragma unroll
      for (int kt = 0; kt < 2; ++kt)
        ap[qt][kt] = mkfrag(pks[qt][2*kt], pks[qt][2*kt + 1]);

    // swapped PV: O^T[d][q] += V^T[d][t] * P[q][t]
#pragma unroll
    for (int dt = 0; dt < 2; ++dt)
#pragma unroll
      for (int qt = 0; qt < 2; ++qt)
#pragma unroll
        for (int kt = 0; kt < 2; ++kt)
          accO[dt][qt] = __builtin_amdgcn_mfma_f32_16x16x32_bf16(
              av[dt][kt], ap[qt][kt], accO[dt][qt], 0, 0, 0);

    // av reload for next tile (covered by accP MFMAs + mask commit + barrier)
#pragma unroll
    for (int dt = 0; dt < 2; ++dt)
#pragma unroll
      for (int kt = 0; kt < 2; ++kt)
        av[dt][kt] = *(const s16x8*)&WhTBH[(size_t)(dt*16 + ln) * S + tnl + kt*32 + lg*8];

    // rowsums via ones-MFMA: accP[qt] += sum_t P[q][t]
#pragma unroll
    for (int qt = 0; qt < 2; ++qt)
#pragma unroll
      for (int kt = 0; kt < 2; ++kt)
        accP[qt] = __builtin_amdgcn_mfma_f32_16x16x32_bf16(
            onesf, ap[qt][kt], accP[qt], 0, 0, 0);

    // commit next mask tile
    if (pf) {
      uint2 u0, u1;
      u0.x = (a0n.x ? 0xFFFFu : 0u) | (a0n.y ? 0xFFFF0000u : 0u);
      u0.y = (a0n.z ? 0xFFFFu : 0u) | (a0n.w ? 0xFFFF0000u : 0u);
      u1.x = (a1n.x ? 0xFFFFu : 0u) | (a1n.y ? 0xFFFF0000u : 0u);
      u1.y = (a1n.z ? 0xFFFFu : 0u) | (a1n.w ? 0xFFFF0000u : 0u);
      *(uint2*)&maskm[cur ^ 1][arow][gc * 8] = u0;
      *(uint2*)&maskm[cur ^ 1][arow][gc * 8 + 4] = u1;
    }
    __syncthreads();
  }

  // ---- epilogue: denominator is per-lane in accP[qt][0] ----
  if (PO == nullptr) {
#pragma unroll
    for (int qt = 0; qt < 2; ++qt) {
      float inv = 1.0f / accP[qt][0];
#pragma unroll
      for (int dt = 0; dt < 2; ++dt) {
        f32x4 o;
#pragma unroll
        for (int r = 0; r < 4; ++r) o[r] = accO[dt][qt][r] * inv;
        *(f32x4*)&out[((size_t)b * S + s0 + qt*16 + ln) * (H * D) + w*32 + dt*16 + g4] = o;
      }
    }
  } else {
    const size_t pbase = (size_t)rbid * H + w;
    float* po = PO + pbase * 1024;
#pragma unroll
    for (int qt = 0; qt < 2; ++qt) {
#pragma unroll
      for (int dt = 0; dt < 2; ++dt)
        *(f32x4*)&po[(qt*16 + ln)*32 + dt*16 + g4] = accO[dt][qt];
      if (lg == 0) PS[pbase * 32 + qt*16 + ln] = accP[qt][0];
    }
  }
}

__global__ __launch_bounds__(256) void gat_reduce(const float* __restrict__ PO,
                                                  const float* __restrict__ PS,
                                                  float* __restrict__ out,
                                                  int nchunks) {
  const int f4 = blockIdx.x * 256 + threadIdx.x;  // f32x4 index over out
  const int d4 = f4 & 31;            // 32 f32x4 per s-row (128 floats)
  const int h = d4 >> 3;
  const int dq = d4 & 7;
  const int s_flat = f4 >> 5;        // b*2048 + s
  const int b = s_flat >> 11, s = s_flat & 2047;
  const int g = b * 64 + (s >> 5), q = s & 31;

  f32x4 acc = {0.f, 0.f, 0.f, 0.f};
  float ps = 0.f;
  for (int c = 0; c < nchunks; ++c) {
    size_t pbase = ((size_t)(c * 512 + g)) * H + h;
    acc += *(const f32x4*)&PO[pbase * 1024 + q*32 + dq*4];
    ps += PS[pbase * 32 + q];
  }
  float inv = 1.0f / ps;
  f32x4 o = acc * inv;
  *(f32x4*)&out[(size_t)f4 * 4] = o;
}

}  // namespace

extern "C" void kernel_launch(void* const* d_in, const int* in_sizes, int n_in,
                              void* d_out, int out_size, void* d_ws, size_t ws_size,
                              hipStream_t stream) {
  const float* feat = (const float*)d_in[0];   // [8,2048,128] f32
  const int* adj    = (const int*)d_in[1];     // [8,2048,2048] i32
  const float* W    = (const float*)d_in[2];   // [4,128,32] f32
  float* out        = (float*)d_out;           // [8,2048,128] f32

  short* Wh  = (short*)d_ws;                             // 4 MiB bf16
  short* WhT = Wh + (size_t)8 * H * S * D;               // 4 MiB bf16
  const size_t whbytes = (size_t)2 * 8 * H * S * D * sizeof(short);
  const size_t chunkPO = (size_t)512 * H * 1024 * sizeof(float);  // 8 MiB
  const size_t chunkPS = (size_t)512 * H * 32 * sizeof(float);    // 256 KiB

  int nchunks = 1;
  if (ws_size >= whbytes + 2 * (chunkPO + chunkPS)) nchunks = 2;

  float* PO = nullptr;
  float* PS = nullptr;
  if (nchunks > 1) {
    PO = (float*)((char*)d_ws + whbytes);
    PS = (float*)((char*)d_ws + whbytes + (size_t)nchunks * chunkPO);
  }

  gat_proj<<<(8 * S) / 64, 256, 0, stream>>>(feat, W, Wh, WhT);
  gat_attn<<<512 * nchunks, 256, 0, stream>>>(adj, Wh, WhT, out, PO, PS, 32 / nchunks);
  if (nchunks > 1) gat_reduce<<<2048, 256, 0, stream>>>(PO, PS, out, nchunks);
}